// Round 3
// baseline (95.277 us; speedup 1.0000x reference)
//
#include <hip/hip_runtime.h>
#include <stdint.h>

// CVKAN layer: out[b,o] = Re( sum_{i,k} basis[b,i,k] * coeffs[i,o,k] + bias[o] )
// basis k<8  = exp(-((x_re[b,i]-g_k)/h)^2), k>=8 uses x_im; g=linspace(-1,1,8), h=2/7
// Output contract (derived R0-R4, verified): out = REAL plane only, (B,16) f32.
//
// R8: trans-pipe + pack reduction (kernel is bound by per-step issue work;
// R5 vs R7 identical 94.43 us with different staging proves the shared inner
// loop is the cost).
//  - Gaussian ladder: on a uniform grid, e_k = 2^{-(u-kD)^2} with
//    u = CS*(t+1), D = sqrt(log2 e).  e_{k+1}/e_k = w * C_k where
//    w = exp2(2*D*CS*(t+1))  (ONE exp) and C_k = e^{-(2k+1)} are constants
//    (D^2 = log2 e exactly).  8 exps -> 2 exps + 14 muls per step.
//    t clamped to [-8,8] (all bases underflow past ~3.5 anyway; avoids
//    inf*0=NaN in w*e0 for pathological inputs).
//  - pack8 (20 insts) -> native __bf16 casts (v_cvt_pk_bf16_f32); proven
//    absmax-safe in R6 (same 0.0625), whose regression was spill (unroll 8 +
//    4 accs), all reverted here: single acc, unroll 4, launch_bounds(256).
//  - LDS coeff layout regrouped to [half][i>>2][i&3][o][8] so each step's
//    wave ds_read_b128 covers 1024 CONTIGUOUS bytes (conflict-free), vs 4
//    stride-256B rows before.

typedef __attribute__((ext_vector_type(8))) short  short8;
typedef __attribute__((ext_vector_type(4))) float  floatx4;
typedef __attribute__((ext_vector_type(8))) __bf16 bf16x8;

__device__ __forceinline__ float fexp2(float x) {
#if __has_builtin(__builtin_amdgcn_exp2f)
  return __builtin_amdgcn_exp2f(x);
#else
  return exp2f(x);
#endif
}

// CS = (7/2)*sqrt(log2 e); w-exponent scale = 2*D*CS = 7*log2 e
#define CVK_CS  4.2039284307525743f
#define CVK_WS  10.098865380412092f

// C_k = e^{-(2k+1)}, k=0..6
__device__ __constant__ const float CVK_C[7] = {
  0.36787944117144233f, 0.049787068367863944f, 0.006737946999085467f,
  9.118819655545162e-4f, 1.2340980408667956e-4f, 1.670170079024566e-5f,
  2.2603294069810542e-6f };

// 8 Gaussian basis values of t -> 8 bf16 via the ladder (2 exps total)
__device__ __forceinline__ short8 basis8(float t) {
  t = fminf(fmaxf(t, -8.f), 8.f);
  const float u  = fmaf(t, CVK_CS, CVK_CS);     // CS*(t+1)
  const float e0 = fexp2(-(u * u));
  const float w  = fexp2(fmaf(t, CVK_WS, CVK_WS));
  float m0 = w * CVK_C[0], m1 = w * CVK_C[1], m2 = w * CVK_C[2],
        m3 = w * CVK_C[3], m4 = w * CVK_C[4], m5 = w * CVK_C[5],
        m6 = w * CVK_C[6];
  float f0 = e0;
  float f1 = f0 * m0;
  float f2 = f1 * m1;
  float f3 = f2 * m2;
  float f4 = f3 * m3;
  float f5 = f4 * m4;
  float f6 = f5 * m5;
  float f7 = f6 * m6;
  union { bf16x8 h; short8 s; } c;
  c.h[0] = (__bf16)f0; c.h[1] = (__bf16)f1; c.h[2] = (__bf16)f2;
  c.h[3] = (__bf16)f3; c.h[4] = (__bf16)f4; c.h[5] = (__bf16)f5;
  c.h[6] = (__bf16)f6; c.h[7] = (__bf16)f7;
  return c.s;
}

__device__ __forceinline__ short8 cast8(const float* v) {
  union { bf16x8 h; short8 s; } c;
#pragma unroll
  for (int k = 0; k < 8; ++k) c.h[k] = (__bf16)v[k];
  return c.s;
}

// block = 256 threads = 4 waves; wave w -> rows [blk*64 + w*16, +16)
// 32 MFMA steps of K=32: steps 0..15 re-half (x_re), 16..31 im-half (x_im).
template <int MODE>
__global__ __launch_bounds__(256)
void cvkan_main(const float* __restrict__ xre, const float* __restrict__ xim,
                const float* __restrict__ cre, const float* __restrict__ cim,
                const float* __restrict__ bre, const float* __restrict__ bim,
                float* __restrict__ out, int out_size_elems) {
  // [half][i>>2][i&3][o][kc]: h*8192 + (i>>2)*512 + (i&3)*128 + o*8 + kc
  // (uint16 units, 32 KB). Per step s the wave reads elems
  // [h*8192 + s*512, +512) = 1024 contiguous bytes -> conflict-free b128.
  __shared__ uint16_t wlds[16384];
  const int tid = threadIdx.x;
  const size_t b0 = (size_t)blockIdx.x * 64;

  // ---- stage+convert re-plane coeffs: 64 KB f32 -> 32 KB bf16 in LDS ----
  {
    const float4* cf = (const float4*)cre;
#pragma unroll
    for (int it = 0; it < 16; ++it) {
      const int idx = it * 1024 + tid * 4;       // element index, 16384 total
      const float4 v = cf[it * 256 + tid];
      const int i = idx >> 8, o = (idx >> 4) & 15, k0 = idx & 15;
      const int dst = ((k0 >> 3) << 13) + ((i >> 2) << 9) + ((i & 3) << 7)
                      + (o << 3) + (k0 & 7);
      unsigned lo = ((__float_as_uint(v.x) + 0x8000u) >> 16) |
                    ((__float_as_uint(v.y) + 0x8000u) & 0xffff0000u);
      unsigned hi = ((__float_as_uint(v.z) + 0x8000u) >> 16) |
                    ((__float_as_uint(v.w) + 0x8000u) & 0xffff0000u);
      *(uint2*)&wlds[dst] = make_uint2(lo, hi);
    }
  }
  __syncthreads();

  const int lane = tid & 63;
  const int wave = tid >> 6;
  const int n  = lane & 15;   // A-row m within tile / B-col o / D-col
  const int q  = lane >> 4;   // quad: i = 4s + q

  const size_t row = b0 + (size_t)(wave * 16 + n);
  const float* xr = xre + row * 64 + q;     // t = xr[4*s]
  const float* xi = xim + row * 64 + q;

  floatx4 accr = {0.f, 0.f, 0.f, 0.f};
  floatx4 acci = {0.f, 0.f, 0.f, 0.f};

  const int bchunk = (q * 16 + n) * 8;      // lane's elem offset in 512 block

  // ---- half 0: re basis (kc 0..7) driven by x_re ----
#pragma unroll 4
  for (int s = 0; s < 16; ++s) {
    const short8 af = basis8(xr[4 * s]);
    const short8 br = *(const short8*)&wlds[s * 512 + bchunk];
    accr = __builtin_amdgcn_mfma_f32_16x16x32_bf16(af, br, accr, 0, 0, 0);
    if constexpr (MODE == 1) {
      const int i = 4 * s + q;
      float c8[8];
      *(float4*)(c8)     = *(const float4*)(cim + (i * 16 + n) * 16);
      *(float4*)(c8 + 4) = *(const float4*)(cim + (i * 16 + n) * 16 + 4);
      const short8 bi = cast8(c8);
      acci = __builtin_amdgcn_mfma_f32_16x16x32_bf16(af, bi, acci, 0, 0, 0);
    }
  }

  // ---- half 1: im basis (kc 8..15) driven by x_im ----
#pragma unroll 4
  for (int s = 0; s < 16; ++s) {
    const short8 af = basis8(xi[4 * s]);
    const short8 br = *(const short8*)&wlds[8192 + s * 512 + bchunk];
    accr = __builtin_amdgcn_mfma_f32_16x16x32_bf16(af, br, accr, 0, 0, 0);
    if constexpr (MODE == 1) {
      const int i = 4 * s + q;
      float c8[8];
      *(float4*)(c8)     = *(const float4*)(cim + (i * 16 + n) * 16 + 8);
      *(float4*)(c8 + 4) = *(const float4*)(cim + (i * 16 + n) * 16 + 12);
      const short8 bi = cast8(c8);
      acci = __builtin_amdgcn_mfma_f32_16x16x32_bf16(af, bi, acci, 0, 0, 0);
    }
  }

  // C/D layout: col = lane&15, row = (lane>>4)*4 + reg  [verified m89/m91]
  const float biasr = bre[n];
  const size_t rowbase = b0 + (size_t)wave * 16;
  const size_t lim = (size_t)out_size_elems;

  if constexpr (MODE == 0) {
#pragma unroll
    for (int r = 0; r < 4; ++r) {
      const int rw = q * 4 + r;
      const size_t idx = (rowbase + rw) * 16 + n;
      if (idx < lim) out[idx] = accr[r] + biasr;
    }
  } else {
    const float biasi = bim[n];
#pragma unroll
    for (int r = 0; r < 4; ++r) {
      const int rw = q * 4 + r;
      const size_t idx = (rowbase + rw) * 16 + n;
      if (2 * idx + 1 < lim) {
        float2 v = make_float2(accr[r] + biasr, acci[r] + biasi);
        *(float2*)(out + 2 * idx) = v;
      }
    }
  }
}

extern "C" void kernel_launch(void* const* d_in, const int* in_sizes, int n_in,
                              void* d_out, int out_size, void* d_ws, size_t ws_size,
                              hipStream_t stream) {
  const float* xre = (const float*)d_in[0];
  const float* xim = (const float*)d_in[1];
  const float* cre = (const float*)d_in[2];
  const float* cim = (const float*)d_in[3];
  const float* bre = (const float*)d_in[4];
  const float* bim = (const float*)d_in[5];
  float* out = (float*)d_out;

  const long long Bn = in_sizes[0] / 64;   // batch rows (65536)
  const int grid = (int)(Bn / 64);         // 64 rows per block

  // mode 1 (interleaved complex) only if the buffer provably holds 2 f32
  // per output element; otherwise mode 0 (real plane only).  [R4: mode 0]
  const int mode = ((long long)out_size >= Bn * 32) ? 1 : 0;

  if (mode == 0) {
    cvkan_main<0><<<grid, 256, 0, stream>>>(xre, xim, cre, cim, bre, bim, out, out_size);
  } else {
    cvkan_main<1><<<grid, 256, 0, stream>>>(xre, xim, cre, cim, bre, bim, out, out_size);
  }
}